// Round 17
// baseline (360.032 us; speedup 1.0000x reference)
//
#include <hip/hip_runtime.h>
#include <math.h>

// ---------------------------------------------------------------------------
// b=1, S=1024, H=16, D=64, HID=1024. All f32; pos int32; out f32.
// Passing R10-R16 semantics (absmax ~7e-3). This round: single change on the
// round-16 proven config (336.0us):
//  gemm_qkv_s48 BK=16 -> BK=32 double-buffered. Halves barrier count per
//  kc=384 panel (24 -> 12 sync rounds; each barrier costs a full waitcnt
//  drain across resident waves — the measured 57.5% VALUBusy vs 67% cap gap).
//  FMA chains: ascending-k within panel, two BK=16 steps == one BK=32 step,
//  identical op sequence -> q/k/v BIT-IDENTICAL. LDS 25.6->51.2KB (cap 3
//  blocks/CU >= current ~2 effective); B staged via proven 8-col+(+64)
//  2-way-free pattern; A via round-0 qkv64's (tid&3)*8 transpose.
// All other kernels unchanged (each the winner of its A/B history).
// ---------------------------------------------------------------------------
#define NEGF  -1e30f
#define TAU   1e-6f

static __device__ __forceinline__ int imin(int a, int b) { return a < b ? a : b; }

static __device__ __forceinline__ void fma44(float A[4][4], const float4 xa, const float4 yb) {
  A[0][0] += xa.x * yb.x; A[0][1] += xa.x * yb.y; A[0][2] += xa.x * yb.z; A[0][3] += xa.x * yb.w;
  A[1][0] += xa.y * yb.x; A[1][1] += xa.y * yb.y; A[1][2] += xa.y * yb.z; A[1][3] += xa.y * yb.w;
  A[2][0] += xa.z * yb.x; A[2][1] += xa.z * yb.y; A[2][2] += xa.z * yb.z; A[2][3] += xa.z * yb.w;
  A[3][0] += xa.w * yb.x; A[3][1] += xa.w * yb.y; A[3][2] += xa.w * yb.z; A[3][3] += xa.w * yb.w;
}

static __device__ __forceinline__ void fold44(float T[4][4], float A[4][4]) {
#pragma unroll
  for (int e = 0; e < 4; ++e)
#pragma unroll
    for (int f = 0; f < 4; ++f) { T[e][f] = __fadd_rn(T[e][f], A[e][f]); A[e][f] = 0.0f; }
}

// ---------------------------------------------------------------------------
// f32 GEMM, 64x64 tile, 256 threads, 4x4/thread, BK=16, sequential FMA over k.
// MODE 0: plain f32; 1: silu; 2: +eps*R residual. Batched via blockIdx.z.
// ---------------------------------------------------------------------------
template <int MODE>
__global__ __launch_bounds__(256) void gemm64(
    const float* __restrict__ A, const float* __restrict__ B, float* __restrict__ C,
    const float* __restrict__ R, const float* __restrict__ eps_p,
    int M, int N, int K, int lda, int ldb, int ldc,
    long sA, long sB, long sC)
{
  const int z = blockIdx.z;
  A += (long)z * sA;
  B += (long)z * sB;
  float* Cf = C + (long)z * sC;
  const float* Rz = (MODE == 2) ? (R + (long)z * sC) : nullptr;

  const int bm = blockIdx.x * 64;
  const int bn = blockIdx.y * 64;
  const int tid = threadIdx.x;
  const int r0 = (tid >> 4) * 4;
  const int c0 = (tid & 15) * 4;

  __shared__ float As[16][68];
  __shared__ float Bs[16][64];

  float acc[4][4] = {};

  const int ar = tid >> 2;
  const int ac = (tid & 3) * 4;
  const int br = tid >> 4;
  const int bc = (tid & 15) * 4;

  for (int kt = 0; kt < K; kt += 16) {
    float4 av = *(const float4*)(A + (long)(bm + ar) * lda + kt + ac);
    float4 bv = *(const float4*)(B + (long)(kt + br) * ldb + bn + bc);
    As[ac + 0][ar] = av.x;
    As[ac + 1][ar] = av.y;
    As[ac + 2][ar] = av.z;
    As[ac + 3][ar] = av.w;
    *(float4*)&Bs[br][bc] = bv;
    __syncthreads();
#pragma unroll
    for (int kk = 0; kk < 16; ++kk) {
      const float4 xa = *(const float4*)&As[kk][r0];
      const float4 yb = *(const float4*)&Bs[kk][c0];
      fma44(acc, xa, yb);
    }
    __syncthreads();
  }

  const float ev = (MODE == 2) ? eps_p[0] : 0.0f;
#pragma unroll
  for (int e = 0; e < 4; ++e)
#pragma unroll
    for (int f = 0; f < 4; ++f) {
      const int r = bm + r0 + e;
      const int c = bn + c0 + f;
      float x = acc[e][f];
      if (MODE == 1) x = x / (1.0f + expf(-x));
      if (MODE == 2) x += ev * Rz[(long)r * ldc + c];
      Cf[(long)r * ldc + c] = x;
    }
}

// ---------------------------------------------------------------------------
// Split-K QKV, 64x128 tile, 4x8 fragments (4+4 cols split at +64 — bank
// conflict-free), BK=32 double-buffered (half the barriers of BK=16).
// Grid (16,8,9): z -> (mat, panel). combine applies the exact
// fl(fl(S1+S2)+S3) fold -> q/k bit-identical.
// ---------------------------------------------------------------------------
__global__ __launch_bounds__(256) void gemm_qkv_s48(
    const float* __restrict__ A,
    const float* __restrict__ Wq, const float* __restrict__ Wk, const float* __restrict__ Wv,
    float* __restrict__ part)
{
  const int z = blockIdx.z;
  const int mat = z % 3;
  const int panel = z / 3;
  const float* B = (mat == 0) ? Wq : (mat == 1) ? Wk : Wv;
  float* P = part + ((long)(mat * 3 + panel) << 20);

  const int k0 = panel * 384;
  const int k1 = (panel == 2) ? 1024 : (k0 + 384);

  const int bm = blockIdx.x * 64;
  const int bn = blockIdx.y * 128;
  const int tid = threadIdx.x;
  const int r0 = (tid >> 4) * 4;    // 4 rows
  const int c0 = (tid & 15) * 4;    // cols c0 and c0+64

  __shared__ float As[2][32][68];
  __shared__ float Bs[2][32][132];

  float aL[4][4] = {}, aR[4][4] = {};

  const int ar = tid >> 2;          // 0..63 A row
  const int ac = (tid & 3) * 8;     // 0,8,16,24 A k-chunk (2 float4)
  const int br = tid >> 3;          // 0..31 B k-row
  const int bc = (tid & 7) * 8;     // B cols bc..bc+7 and +64

  {
    float4 a0 = *(const float4*)(A + (long)(bm + ar) * 1024 + k0 + ac);
    float4 a1 = *(const float4*)(A + (long)(bm + ar) * 1024 + k0 + ac + 4);
    float4 b0 = *(const float4*)(B + (long)(k0 + br) * 1024 + bn + bc);
    float4 b1 = *(const float4*)(B + (long)(k0 + br) * 1024 + bn + bc + 4);
    float4 b2 = *(const float4*)(B + (long)(k0 + br) * 1024 + bn + 64 + bc);
    float4 b3 = *(const float4*)(B + (long)(k0 + br) * 1024 + bn + 64 + bc + 4);
    As[0][ac + 0][ar] = a0.x; As[0][ac + 1][ar] = a0.y;
    As[0][ac + 2][ar] = a0.z; As[0][ac + 3][ar] = a0.w;
    As[0][ac + 4][ar] = a1.x; As[0][ac + 5][ar] = a1.y;
    As[0][ac + 6][ar] = a1.z; As[0][ac + 7][ar] = a1.w;
    *(float4*)&Bs[0][br][bc]          = b0;
    *(float4*)&Bs[0][br][bc + 4]      = b1;
    *(float4*)&Bs[0][br][64 + bc]     = b2;
    *(float4*)&Bs[0][br][64 + bc + 4] = b3;
  }
  __syncthreads();

  int cur = 0;
  for (int kt = k0; kt < k1; kt += 32) {
    const bool more = (kt + 32 < k1);
    float4 a0n, a1n, b0n, b1n, b2n, b3n;
    if (more) {
      a0n = *(const float4*)(A + (long)(bm + ar) * 1024 + kt + 32 + ac);
      a1n = *(const float4*)(A + (long)(bm + ar) * 1024 + kt + 32 + ac + 4);
      b0n = *(const float4*)(B + (long)(kt + 32 + br) * 1024 + bn + bc);
      b1n = *(const float4*)(B + (long)(kt + 32 + br) * 1024 + bn + bc + 4);
      b2n = *(const float4*)(B + (long)(kt + 32 + br) * 1024 + bn + 64 + bc);
      b3n = *(const float4*)(B + (long)(kt + 32 + br) * 1024 + bn + 64 + bc + 4);
    }
#pragma unroll
    for (int kk = 0; kk < 32; ++kk) {
      const float4 xa = *(const float4*)&As[cur][kk][r0];
      const float4 y0 = *(const float4*)&Bs[cur][kk][c0];
      const float4 y1 = *(const float4*)&Bs[cur][kk][64 + c0];
      fma44(aL, xa, y0);
      fma44(aR, xa, y1);
    }
    if (more) {
      const int nxt = cur ^ 1;
      As[nxt][ac + 0][ar] = a0n.x; As[nxt][ac + 1][ar] = a0n.y;
      As[nxt][ac + 2][ar] = a0n.z; As[nxt][ac + 3][ar] = a0n.w;
      As[nxt][ac + 4][ar] = a1n.x; As[nxt][ac + 5][ar] = a1n.y;
      As[nxt][ac + 6][ar] = a1n.z; As[nxt][ac + 7][ar] = a1n.w;
      *(float4*)&Bs[nxt][br][bc]          = b0n;
      *(float4*)&Bs[nxt][br][bc + 4]      = b1n;
      *(float4*)&Bs[nxt][br][64 + bc]     = b2n;
      *(float4*)&Bs[nxt][br][64 + bc + 4] = b3n;
      __syncthreads();
      cur = nxt;
    }
  }

#pragma unroll
  for (int e = 0; e < 4; ++e) {
    float* prow = P + (long)(bm + r0 + e) * 1024 + bn;
#pragma unroll
    for (int f = 0; f < 4; ++f) {
      prow[c0 + f]      = aL[e][f];
      prow[64 + c0 + f] = aR[e][f];
    }
  }
}

// ---------------------------------------------------------------------------
// Fused panel-combine + RoPE. Bit-identical to combine_qkv -> rope_apply.
// ---------------------------------------------------------------------------
__global__ __launch_bounds__(256) void combine_rope(
    const float4* __restrict__ part, const float2* __restrict__ tab,
    float4* __restrict__ q, float4* __restrict__ k, float4* __restrict__ v)
{
  const int g = blockIdx.x * 256 + threadIdx.x;
  if (g < 262144) {
    const int buf = g >> 17;            // 0=q, 1=k
    const int rem = g & 131071;
    const int s   = rem >> 7;
    const int hx  = (rem >> 3) & 15;
    const int t4  = rem & 7;
    const int w   = s * 256 + hx * 16 + t4;   // float4 idx of lo (d in [0,32))
    const long b  = (long)(buf * 3) << 18;

    const float4 a0 = part[b + w];
    const float4 a1 = part[b + (1L << 18) + w];
    const float4 a2 = part[b + (2L << 18) + w];
    const float4 c0 = part[b + w + 8];
    const float4 c1 = part[b + (1L << 18) + w + 8];
    const float4 c2 = part[b + (2L << 18) + w + 8];

    float lo[4], hi[4];
    lo[0] = __fadd_rn(__fadd_rn(a0.x, a1.x), a2.x);
    lo[1] = __fadd_rn(__fadd_rn(a0.y, a1.y), a2.y);
    lo[2] = __fadd_rn(__fadd_rn(a0.z, a1.z), a2.z);
    lo[3] = __fadd_rn(__fadd_rn(a0.w, a1.w), a2.w);
    hi[0] = __fadd_rn(__fadd_rn(c0.x, c1.x), c2.x);
    hi[1] = __fadd_rn(__fadd_rn(c0.y, c1.y), c2.y);
    hi[2] = __fadd_rn(__fadd_rn(c0.z, c1.z), c2.z);
    hi[3] = __fadd_rn(__fadd_rn(c0.w, c1.w), c2.w);

    float ol[4], oh[4];
#pragma unroll
    for (int c = 0; c < 4; ++c) {
      const int t = t4 * 4 + c;
      const float2 cs = tab[s * 32 + t];
      const float x1 = lo[c];
      const float x2 = hi[c];
      ol[c] = __fadd_rn(__fmul_rn(x1, cs.x), __fmul_rn(-x2, cs.y));
      oh[c] = __fadd_rn(__fmul_rn(x2, cs.x), __fmul_rn(x1, cs.y));
    }
    float4* dst = buf ? k : q;
    dst[w]     = make_float4(ol[0], ol[1], ol[2], ol[3]);
    dst[w + 8] = make_float4(oh[0], oh[1], oh[2], oh[3]);
  } else {
    const int w = g - 262144;           // 0..262143
    const long b = (long)6 << 18;
    const float4 s0 = part[b + w];
    const float4 s1 = part[b + (1L << 18) + w];
    const float4 s2 = part[b + (2L << 18) + w];
    float4 r;
    r.x = __fadd_rn(__fadd_rn(s0.x, s1.x), s2.x);
    r.y = __fadd_rn(__fadd_rn(s0.y, s1.y), s2.y);
    r.z = __fadd_rn(__fadd_rn(s0.z, s1.z), s2.z);
    r.w = __fadd_rn(__fadd_rn(s0.w, s1.w), s2.w);
    v[w] = r;
  }
}

// ---------------------------------------------------------------------------
// gemm_out split-K combine: dst = fl(p0 + p1), 1M floats as float4.
// ---------------------------------------------------------------------------
__global__ __launch_bounds__(256) void combine_out(
    const float4* __restrict__ p, float4* __restrict__ dst)
{
  const int idx = blockIdx.x * 256 + threadIdx.x;   // 0..262143
  const float4 a = p[idx];
  const float4 b = p[idx + (1 << 18)];
  float4 r;
  r.x = __fadd_rn(a.x, b.x);
  r.y = __fadd_rn(a.y, b.y);
  r.z = __fadd_rn(a.z, b.z);
  r.w = __fadd_rn(a.w, b.w);
  dst[idx] = r;
}

// ---------------------------------------------------------------------------
// Fallback fused QKV (round-0 proven). Used when workspace < 64MB.
// ---------------------------------------------------------------------------
__global__ __launch_bounds__(256) void gemm_qkv64(
    const float* __restrict__ A,
    const float* __restrict__ Wq, const float* __restrict__ Wk, const float* __restrict__ Wv,
    float* __restrict__ qo, float* __restrict__ ko, float* __restrict__ vo)
{
  const int z = blockIdx.z;
  const float* B = (z == 0) ? Wq : (z == 1) ? Wk : Wv;
  float* C = (z == 0) ? qo : (z == 1) ? ko : vo;

  const int bm = blockIdx.x * 64;
  const int bn = blockIdx.y * 64;
  const int tid = threadIdx.x;
  const int r0 = (tid >> 4) * 4;
  const int c0 = (tid & 15) * 4;

  __shared__ float As[2][32][68];
  __shared__ float Bs[2][32][64];

  float acc[4][4] = {};
  float tot[4][4] = {};

  const int ar = tid >> 2;
  const int ac = (tid & 3) * 8;
  const int br = tid >> 3;
  const int bc = (tid & 7) * 8;

  {
    float4 a0 = *(const float4*)(A + (long)(bm + ar) * 1024 + ac);
    float4 a1 = *(const float4*)(A + (long)(bm + ar) * 1024 + ac + 4);
    float4 b0 = *(const float4*)(B + (long)br * 1024 + bn + bc);
    float4 b1 = *(const float4*)(B + (long)br * 1024 + bn + bc + 4);
    As[0][ac + 0][ar] = a0.x; As[0][ac + 1][ar] = a0.y;
    As[0][ac + 2][ar] = a0.z; As[0][ac + 3][ar] = a0.w;
    As[0][ac + 4][ar] = a1.x; As[0][ac + 5][ar] = a1.y;
    As[0][ac + 6][ar] = a1.z; As[0][ac + 7][ar] = a1.w;
    *(float4*)&Bs[0][br][bc] = b0;
    *(float4*)&Bs[0][br][bc + 4] = b1;
  }
  __syncthreads();

  int cur = 0;
  for (int kt = 0; kt < 1024; kt += 32) {
    const bool more = (kt + 32 < 1024);
    float4 a0n, a1n, b0n, b1n;
    if (more) {
      a0n = *(const float4*)(A + (long)(bm + ar) * 1024 + kt + 32 + ac);
      a1n = *(const float4*)(A + (long)(bm + ar) * 1024 + kt + 32 + ac + 4);
      b0n = *(const float4*)(B + (long)(kt + 32 + br) * 1024 + bn + bc);
      b1n = *(const float4*)(B + (long)(kt + 32 + br) * 1024 + bn + bc + 4);
    }
    if (kt == 384 || kt == 768) {
      fold44(tot, acc);
    }
#pragma unroll
    for (int kk = 0; kk < 32; ++kk) {
      const float4 xa = *(const float4*)&As[cur][kk][r0];
      const float4 yb = *(const float4*)&Bs[cur][kk][c0];
      fma44(acc, xa, yb);
    }
    if (more) {
      const int nxt = cur ^ 1;
      As[nxt][ac + 0][ar] = a0n.x; As[nxt][ac + 1][ar] = a0n.y;
      As[nxt][ac + 2][ar] = a0n.z; As[nxt][ac + 3][ar] = a0n.w;
      As[nxt][ac + 4][ar] = a1n.x; As[nxt][ac + 5][ar] = a1n.y;
      As[nxt][ac + 6][ar] = a1n.z; As[nxt][ac + 7][ar] = a1n.w;
      *(float4*)&Bs[nxt][br][bc] = b0n;
      *(float4*)&Bs[nxt][br][bc + 4] = b1n;
      __syncthreads();
      cur = nxt;
    }
  }

#pragma unroll
  for (int e = 0; e < 4; ++e)
#pragma unroll
    for (int f = 0; f < 4; ++f)
      C[(long)(bm + r0 + e) * 1024 + bn + c0 + f] = __fadd_rn(tot[e][f], acc[e][f]);
}

// ---------------------------------------------------------------------------
// RoPE cos/sin table: bit-identical double-path math.
// ---------------------------------------------------------------------------
__global__ __launch_bounds__(256) void rope_table(
    const int* __restrict__ pos_ids, float2* __restrict__ tab)
{
  const int g = blockIdx.x * 256 + threadIdx.x;   // 0..32767
  const int t = g & 31;
  const int s = g >> 5;

  const float e = (float)(2 * t) / 64.0f;
  const float p32 = (float)pow(10000.0, (double)e);
  const float inv = __fdiv_rn(1.0f, p32);
  const float posf = (float)pos_ids[s];
  const float ang = __fmul_rn(posf, inv);
  tab[g] = make_float2((float)cos((double)ang), (float)sin((double)ang));
}

// ---------------------------------------------------------------------------
// RoPE apply (memory-only). Fallback path only.
// ---------------------------------------------------------------------------
__global__ __launch_bounds__(256) void rope_apply(float* __restrict__ q,
                                                  float* __restrict__ kb,
                                                  const float2* __restrict__ tab)
{
  const int g = blockIdx.x * blockDim.x + threadIdx.x;
  const int t = g & 31;
  const int h = (g >> 5) & 15;
  const int s = (g >> 9) & 1023;
  const int buf = g >> 19;
  float* p = buf ? kb : q;

  const float2 cs = tab[s * 32 + t];
  const float c  = cs.x;
  const float sn = cs.y;

  const int base = s * 1024 + h * 64;
  const float x1 = p[base + t];
  const float x2 = p[base + t + 32];
  p[base + t]      = __fadd_rn(__fmul_rn(x1, c), __fmul_rn(-x2, sn));
  p[base + t + 32] = __fadd_rn(__fmul_rn(x2, c), __fmul_rn(x1, sn));
}

// ---------------------------------------------------------------------------
// Score GEMM (round-0 proven), causal lower-triangle 64x64 tiles (136/head).
// ---------------------------------------------------------------------------
__global__ __launch_bounds__(256) void gemm_score(
    const float* __restrict__ q, const float* __restrict__ kb,
    float* __restrict__ S, int headBase)
{
  const int x = blockIdx.x;
  int bmT = 0;
  while ((bmT + 1) * (bmT + 2) / 2 <= x) ++bmT;
  const int bnT = x - bmT * (bmT + 1) / 2;

  const int hl = blockIdx.y;
  const int off = (headBase + hl) * 64;
  const int bm = bmT * 64;
  const int bn = bnT * 64;
  const int tid = threadIdx.x;
  const int r0 = (tid >> 4) * 4;
  const int c0 = (tid & 15) * 4;

  __shared__ float As[16][68];
  __shared__ float Bs[16][68];

  float acc[4][4] = {};

  const int ar = tid >> 2;
  const int ac = (tid & 3) * 4;

  for (int kt = 0; kt < 64; kt += 16) {
    float4 av = *(const float4*)(q  + (long)(bm + ar) * 1024 + off + kt + ac);
    float4 bv = *(const float4*)(kb + (long)(bn + ar) * 1024 + off + kt + ac);
    As[ac + 0][ar] = av.x; As[ac + 1][ar] = av.y;
    As[ac + 2][ar] = av.z; As[ac + 3][ar] = av.w;
    Bs[ac + 0][ar] = bv.x; Bs[ac + 1][ar] = bv.y;
    Bs[ac + 2][ar] = bv.z; Bs[ac + 3][ar] = bv.w;
    __syncthreads();
#pragma unroll
    for (int kk = 0; kk < 16; ++kk) {
      const float4 xa = *(const float4*)&As[kk][r0];
      const float4 yb = *(const float4*)&Bs[kk][c0];
      fma44(acc, xa, yb);
    }
    __syncthreads();
  }

#pragma unroll
  for (int e = 0; e < 4; ++e)
#pragma unroll
    for (int f = 0; f < 4; ++f)
      S[((long)hl * 1024 + bm + r0 + e) * 1024 + bn + c0 + f] = acc[e][f] * 0.125f;
}

// ---------------------------------------------------------------------------
// Selection + aggregation, WAVE-PER-ROW, STRIDED layout (agg6, round-12).
// ---------------------------------------------------------------------------
#define UFV(m) ((raw[m] >= 0.2f) ? __float_as_uint(raw[m]) : 0u)

__global__ __launch_bounds__(256) void select_agg6(
    const float* __restrict__ S, const float* __restrict__ v,
    float* __restrict__ comb, int headBase)
{
  const int tid = threadIdx.x;
  const int lane = tid & 63;
  const int wid = tid >> 6;
  const int i = blockIdx.x * 4 + wid;     // row 0..1023
  const int hl = blockIdx.y;
  const int h = headBase + hl;

  __shared__ int histS[4][256];
  __shared__ unsigned listS[4][128];
  int* hist = histS[wid];
  unsigned* list = listS[wid];

  const int nlayer = (i + 63) >> 6;       // wave-uniform layer count
  const unsigned long long ltm = (1ull << lane) - 1ull;

  // ---- load row: layer m, j = 64m + lane (coalesced 256B/layer) ----
  const float* row = S + ((long)hl * 1024 + i) * 1024;
  float raw[16];
#pragma unroll
  for (int m = 0; m < 16; ++m) raw[m] = 0.0f;
#pragma unroll
  for (int m = 0; m < 16; ++m) {
    if (m < nlayer) {
      const int j = m * 64 + lane;
      if (j < i) raw[m] = row[j];
    }
  }

  const int kk = (i > 0) ? (i + 9) / 10 : 0;
  unsigned V = 0u;
  int need_eq = 0;
  unsigned fmask = 0u;

  if (kk > 0) {
    // ---- pass-0 packed counts over the only possible top bytes ----
    int c3E = 0, c3F = 0, cHI = 0;
    bool anyBig = false;
#pragma unroll
    for (int m = 0; m < 16; ++m) {
      if (m < nlayer) {
        const unsigned u = UFV(m);
        if (u != 0u) {
          const unsigned tb = u >> 24;
          if (tb == 0x3Eu) ++c3E;
          else if (tb == 0x3Fu) ++c3F;
          else { ++cHI; if (tb > 0x40u) anyBig = true; }
        }
      }
    }
    const bool fastOK = (__ballot(anyBig) == 0ull);
    unsigned pk = (unsigned)c3E | ((unsigned)c3F << 10) | ((unsigned)cHI << 20);
#pragma unroll
    for (int off = 1; off < 64; off <<= 1)
      pk += (unsigned)__shfl_xor((int)pk, off, 64);
    const int t3E = (int)(pk & 1023u);
    const int t3F = (int)((pk >> 10) & 1023u);
    const int tHI = (int)((pk >> 20) & 1023u);
    const int totNZ = t3E + t3F + tHI;

    unsigned prefix = 0;
    int rk = kk;
    bool done = false;
    for (int pass = 0; pass < 4 && !done; ++pass) {
      const int shift = 24 - 8 * pass;
      if (pass == 0 && fastOK) {
        if (totNZ < rk) {
          V = 0u; need_eq = rk - totNZ; done = true;
        } else {
          int selBin, scnt;
          if (tHI >= rk)            { selBin = 0x40; scnt = tHI; }
          else if (tHI + t3F >= rk) { selBin = 0x3F; scnt = t3F; rk -= tHI; }
          else                      { selBin = 0x3E; scnt = t3E; rk -= tHI + t3F; }
          prefix = (unsigned)selBin;
          if (rk == scnt) {
            unsigned vm = 0xFFFFFFFFu;
#pragma unroll
            for (int m = 0; m < 16; ++m) {
              if (m < nlayer) {
                const unsigned u = UFV(m);
                if (u != 0u && (u >> shift) == prefix && u < vm) vm = u;
              }
            }
#pragma unroll
            for (int off = 1; off < 64; off <<= 1) {
              const unsigned o = (unsigned)__shfl_xor((int)vm, off, 64);
              if (o < vm) vm = o;
            }
            V = vm; need_eq = 0x3FFFFFFF; done = true;
          }
        }
        continue;
      }
      // ---- generic pass (atomic hist; pass 0 only via fallback) ----
      *(int4*)&hist[lane * 4] = make_int4(0, 0, 0, 0);
      asm volatile("s_waitcnt lgkmcnt(0)" ::: "memory");
      __builtin_amdgcn_sched_barrier(0);
#pragma unroll
      for (int m = 0; m < 16; ++m) {
        if (m < nlayer) {
          const unsigned u = UFV(m);
          if (u != 0u && (pass == 0 || (u >> (shift + 8)) == prefix))
            atomicAdd(&hist[(u >> shift) & 0xFF], 1);
        }
      }
      asm volatile("s_waitcnt lgkmcnt(0)" ::: "memory");
      __builtin_amdgcn_sched_barrier(0);
      const int4 hv = *(const int4*)&hist[lane * 4];
      const int s = hv.x + hv.y + hv.z + hv.w;
      int suf = s;
#pragma unroll
      for (int off = 1; off < 64; off <<= 1) {
        const int o = __shfl_down(suf, off, 64);
        if (lane + off < 64) suf += o;
      }
      const int tot = __shfl(suf, 0, 64);
      if (pass == 0 && tot < rk) {
        V = 0u; need_eq = rk - tot; done = true;
      } else {
        const int above = suf - s;
        const int sfx3 = above + hv.w;
        const int sfx2 = sfx3 + hv.z;
        const int sfx1 = sfx2 + hv.y;
        const int sfx0 = suf;
        int mbin = -1, mh = 0, msfx = 0;
        if (!(pass == 0 && lane == 0) && sfx0 >= rk && sfx0 - hv.x < rk) { mbin = lane * 4 + 0; mh = hv.x; msfx = sfx0; }
        if (sfx1 >= rk && sfx1 - hv.y < rk) { mbin = lane * 4 + 1; mh = hv.y; msfx = sfx1; }
        if (sfx2 >= rk && sfx2 - hv.z < rk) { mbin = lane * 4 + 2; mh = hv.z; msfx = sfx2; }
        if (sfx3 >= rk && sfx3 - hv.w < rk) { mbin = lane * 4 + 3; mh = hv.w; msfx = sfx3; }
        const unsigned long long bal = __ballot(mbin >= 0);
        const int src = (int)__ffsll((unsigned long long)bal) - 1;
        const int selBin = __shfl(mbin, src, 64) & 0xFF;
        const int scnt = __shfl(mh, src, 64);
        const int ssfx = __shfl(msfx, src, 64);
        prefix = (prefix << 8) | (unsigned)selBin;
        rk = rk - (ssfx - scnt);
        if (rk == scnt) {
          unsigned vm = 0xFFFFFFFFu;
#pragma unroll
          for (int m = 0; m < 16; ++m) {
            if (m < nlayer) {
              const unsigned u = UFV(m);
              if (u != 0u && (u >> shift) == prefix && u < vm) vm = u;
            }
          }
#pragma unroll
          for (int off = 1; off < 64; off <<= 1) {
            const unsigned o = (unsigned)__shfl_xor((int)vm, off, 64);
            if (o < vm) vm = o;
          }
          V = vm; need_eq = 0x3FFFFFFF; done = true;
        }
      }
    }
    if (!done) { V = prefix; need_eq = rk; }

    // ---- f0 flags + stable tie-break via per-layer ballots (j order) ----
    int prefEq = 0;
#pragma unroll
    for (int m = 0; m < 16; ++m) {
      if (m < nlayer) {
        const int j = m * 64 + lane;
        const bool validm = (j < i);
        const unsigned u = UFV(m);
        const bool eq = validm && (u == V);
        const unsigned long long bal = __ballot(eq);
        if (validm) {
          if (u > V) fmask |= (1u << m);
          else if (eq) {
            const int excl = prefEq + __popcll(bal & ltm);
            if (excl < need_eq) fmask |= (1u << m);
          }
        }
        prefEq += (int)__popcll(bal);
      }
    }
  }

  // ---- ambiguity hypothesis (all wave-level reduces; uniform result) ----
  int hypOut = -1, hypIn = -1;
  if (kk > 0 && kk < i) {
    unsigned wmax = 0u;
    int mIn = -1;
    unsigned long long tbIn = ~0ull, tbOut = ~0ull;
#pragma unroll
    for (int m = 0; m < 16; ++m) {
      if (m < nlayer) {
        const int j = m * 64 + lane;
        if (j < i) {
          const unsigned u = UFV(m);
          if ((fmask >> m) & 1u) {
            if (u == V && j > mIn) mIn = j;
            const float fv = __uint_as_float(u);
            const float dd = fv - 0.2f;
            if (fv >= 0.2f && dd < TAU) {
              const unsigned long long p = (((unsigned long long)__float_as_uint(dd)) << 32) | (unsigned)j;
              if (p < tbIn) tbIn = p;
            }
          } else {
            if (u > wmax) wmax = u;
            if (raw[m] < 0.2f) {
              const float dd = 0.2f - raw[m];
              if (dd < TAU) {
                const unsigned long long p = (((unsigned long long)__float_as_uint(dd)) << 32) | (unsigned)j;
                if (p < tbOut) tbOut = p;
              }
            }
          }
        }
      }
    }
#pragma unroll
    for (int off = 1; off < 64; off <<= 1) {
      const unsigned ow = (unsigned)__shfl_xor((int)wmax, off, 64);
      if (ow > wmax) wmax = ow;
      const int om = __shfl_xor(mIn, off, 64);
      if (om > mIn) mIn = om;
      const unsigned long long oi = __shfl_xor(tbIn, off, 64);
      if (oi < tbIn) tbIn = oi;
      const unsigned long long oo = __shfl_xor(tbOut, off, 64);
      if (oo < tbOut) tbOut = oo;
    }
    int outMin = 0x7FFFFFFF;
#pragma unroll
    for (int m = 0; m < 16; ++m) {
      if (m < nlayer) {
        const int j = m * 64 + lane;
        if (j < i && !((fmask >> m) & 1u) && UFV(m) == wmax) {
          if (j < outMin) outMin = j;
        }
      }
    }
#pragma unroll
    for (int off = 1; off < 64; off <<= 1) {
      const int o = __shfl_xor(outMin, off, 64);
      if (o < outMin) outMin = o;
    }
    float bestD = TAU;
    int oI = -1, nI = -1;
    if (outMin != 0x7FFFFFFF && mIn >= 0) {
      const float Vf = __uint_as_float(V);
      const float Wf = __uint_as_float(wmax);
      if (!(wmax == V && V == 0u)) {
        const float gapA = Vf - Wf;
        if (gapA < bestD) { bestD = gapA; oI = mIn; nI = outMin; }
      }
      if (tbIn != ~0ull) {
        const float d = __uint_as_float((unsigned)(tbIn >> 32));
        const int jj = (int)(tbIn & 0xFFFFFFFFu);
        const bool noop = (wmax == 0u && jj < outMin);
        if (!noop && d < bestD) { bestD = d; oI = jj; nI = outMin; }
      }
      if (tbOut != ~0ull && Vf <= 0.2f) {
        const float d = __uint_as_float((unsigned)(tbOut >> 32));
        const int jj = (int)(tbOut & 0xFFFFFFFFu);
        if (d < bestD) { bestD = d; oI = mIn; nI = jj; }
      }
    }
    hypOut = oI; hypIn = nI;
  }

  // ---- compaction (j-ascending) via per-layer ballots ----
  const bool amb = (hypOut >= 0);
  int base = 0;
#pragma unroll
  for (int m = 0; m < 16; ++m) {
    if (m < nlayer) {
      const int j = m * 64 + lane;
      const bool validm = (j < i);
      const unsigned f0b = (fmask >> m) & 1u;
      int s1 = (int)f0b;
      if (amb) { if (j == hypOut) s1 = 0; if (j == hypIn) s1 = 1; }
      const bool sel = validm && ((f0b | (unsigned)s1) != 0u);
      const unsigned long long bal = __ballot(sel);
      if (sel) {
        const int pos = base + (int)__popcll(bal & ltm);
        list[pos] = (unsigned)j | (f0b << 10) | ((unsigned)s1 << 11);
      }
      base += (int)__popcll(bal);
    }
  }
  const int L = base;   // wave-uniform
  asm volatile("s_waitcnt lgkmcnt(0)" ::: "memory");
  __builtin_amdgcn_sched_barrier(0);

  const float denom = (float)(kk > 0 ? kk : 1);
  const float* vcol = v + h * 64 + lane;
  float* crow = comb + ((long)(h * 1024 + i)) * 256;

  if (!amb) {
    float sum0 = 0, sq0 = 0, mx0 = NEGF;
    for (int e2 = 0; e2 < L; e2 += 4) {
      const uint4 en4 = *(const uint4*)&list[e2];
      float v0 = 0, v1 = 0, v2 = 0, v3 = 0;
      const bool b0 = (e2 + 0 < L), b1 = (e2 + 1 < L), b2 = (e2 + 2 < L), b3 = (e2 + 3 < L);
      if (b0) v0 = vcol[(long)(en4.x & 1023) * 1024];
      if (b1) v1 = vcol[(long)(en4.y & 1023) * 1024];
      if (b2) v2 = vcol[(long)(en4.z & 1023) * 1024];
      if (b3) v3 = vcol[(long)(en4.w & 1023) * 1024];
      if (b0) { sum0 += v0; sq0 += v0 * v0; mx0 = fmaxf(mx0, v0); }
      if (b1) { sum0 += v1; sq0 += v1 * v1; mx0 = fmaxf(mx0, v1); }
      if (b2) { sum0 += v2; sq0 += v2 * v2; mx0 = fmaxf(mx0, v2); }
      if (b3) { sum0 += v3; sq0 += v3 * v3; mx0 = fmaxf(mx0, v3); }
    }
    const float mean0 = sum0 / denom;
    const float var0 = fmaxf(sq0 / denom - mean0 * mean0, 0.0f);
    const float mx0o = (kk > 0) ? mx0 : 0.0f;
    crow[lane]       = sum0;
    crow[64 + lane]  = mean0;
    crow[128 + lane] = mx0o;
    crow[192 + lane] = var0;
  } else {
    float sum0 = 0, sq0 = 0, mx0 = NEGF, sum1 = 0, sq1 = 0, mx1 = NEGF;
    for (int e2 = 0; e2 < L; e2 += 4) {
      const uint4 en4 = *(const uint4*)&list[e2];
      const unsigned w0 = (e2 + 0 < L) ? en4.x : 0u;
      const unsigned w1 = (e2 + 1 < L) ? en4.y : 0u;
      const unsigned w2 = (e2 + 2 < L) ? en4.z : 0u;
      const unsigned w3 = (e2 + 3 < L) ? en4.w : 0u;
      float v0 = 0, v1 = 0, v2 = 0, v3 = 0;
      if (w0) v0 = vcol[(long)(w0 & 1023) * 1024];
      if (w1) v1 = vcol[(long)(w1 & 1023) * 1024];
      if (w2) v2 = vcol[(long)(w2 & 1023) * 1024];
      if (w3) v3 = vcol[(long)(w3 & 1023) * 1024];
      if (w0 & (1u << 10)) { sum0 += v0; sq0 += v0 * v0; mx0 = fmaxf(mx0, v0); }
      if (w0 & (1u << 11)) { sum1 += v0; sq1 += v0 * v0; mx1 = fmaxf(mx1, v0); }
      if (w1 & (1u << 10)) { sum0 += v1; sq0 += v1 * v1; mx0 = fmaxf(mx0, v1); }
      if (w1 & (1u << 11)) { sum1 += v1; sq1 += v1 * v1; mx1 = fmaxf(mx1, v1); }
      if (w2 & (1u << 10)) { sum0 += v2; sq0 += v2 * v2; mx0 = fmaxf(mx0, v2); }
      if (w2 & (1u << 11)) { sum1 += v2; sq1 += v2 * v2; mx1 = fmaxf(mx1, v2); }
      if (w3 & (1u << 10)) { sum0 += v3; sq0 += v3 * v3; mx0 = fmaxf(mx0, v3); }
      if (w3 & (1u << 11)) { sum1 += v3; sq1 += v3 * v3; mx1 = fmaxf(mx1, v3); }
    }
    const float mean0 = sum0 / denom, mean1 = sum1 / denom;
    const float var0 = fmaxf(sq0 / denom - mean0 * mean0, 0.0f);
    const float var1 = fmaxf(sq1 / denom - mean1 * mean1, 0.0f);
    const float mx0o = (kk > 0) ? mx0 : 0.0f;
    const float mx1o = (kk > 0) ? mx1 : 0.0f;
    crow[lane]       = 0.5f * (sum0 + sum1);
    crow[64 + lane]  = 0.5f * (mean0 + mean1);
    crow[128 + lane] = 0.5f * (mx0o + mx1o);
    crow[192 + lane] = 0.5f * (var0 + var1);
  }
}

// ---------------------------------------------------------------------------
// Launch
// ---------------------------------------------------------------------------
extern "C" void kernel_launch(void* const* d_in, const int* in_sizes, int n_in,
                              void* d_out, int out_size, void* d_ws, size_t ws_size,
                              hipStream_t stream)
{
  const float* hidden = (const float*)d_in[0];
  const float* Wq = (const float*)d_in[1];
  const float* Wk = (const float*)d_in[2];
  const float* Wv = (const float*)d_in[3];
  const float* Wo = (const float*)d_in[4];
  const float* W1 = (const float*)d_in[5];
  const float* W2 = (const float*)d_in[6];
  const float* eps = (const float*)d_in[7];
  const int* pos = (const int*)d_in[8];

  const size_t MB = 1024UL * 1024UL;
  int G = 4;
  if (ws_size >= 28 * MB + 64 * MB) G = 16;
  else if (ws_size >= 28 * MB + 32 * MB) G = 8;

  float* q      = (float*)d_ws;
  float* kbuf   = q + (1 << 20);
  float* v      = kbuf + (1 << 20);
  float* comb   = v + (1 << 20);
  float* scores = comb + (1 << 22);
  float* h1     = scores;               // overlay (scores dead after select)
  float* ho     = scores + (1 << 21);
  // Overlays on comb (16MB):
  //  - rope table (256KB): used before select writes comb.
  //  - gemm_out partials (8MB): used after gemm64<1> consumed comb.
  float2* tab   = (float2*)comb;
  float* parts  = comb;

  const dim3 blk(256);

  rope_table<<<128, blk, 0, stream>>>(pos, tab);

  if (ws_size >= 64 * MB) {
    // split-K over kc=384 panels; partials (36MB) overlay scores region;
    // fused combine+rope writes rotated q/k and plain v.
    float* part = scores;
    gemm_qkv_s48<<<dim3(16, 8, 9), blk, 0, stream>>>(hidden, Wq, Wk, Wv, part);
    combine_rope<<<2048, blk, 0, stream>>>((const float4*)part, tab,
                                           (float4*)q, (float4*)kbuf, (float4*)v);
  } else {
    gemm_qkv64<<<dim3(16, 16, 3), blk, 0, stream>>>(hidden, Wq, Wk, Wv, q, kbuf, v);
    rope_apply<<<4096, blk, 0, stream>>>(q, kbuf, tab);
  }

  for (int g = 0; g < 16; g += G) {
    gemm_score<<<dim3(136, G), blk, 0, stream>>>(q, kbuf, scores, g);
    select_agg6<<<dim3(256, G), blk, 0, stream>>>(scores, v, comb, g);
  }

  gemm64<1><<<dim3(16, 2, 16), blk, 0, stream>>>(comb, W1, h1, nullptr, nullptr,
      1024, 128, 256, 256, 128, 128, (long)1024 * 256, (long)256 * 128, (long)1024 * 128);

  gemm64<2><<<dim3(16, 1, 16), blk, 0, stream>>>(h1, W2, ho, v, eps,
      1024, 64, 128, 128, 64, 1024, (long)1024 * 128, (long)128 * 64, 64);

  // Output projection: 64x64 tile, split-K=2 (z picks k-half), then combine.
  gemm64<0><<<dim3(16, 16, 2), blk, 0, stream>>>(ho, Wo, parts, nullptr, nullptr,
      1024, 1024, 512, 1024, 1024, 1024, 512, (long)512 * 1024, (long)1 << 20);
  combine_out<<<dim3(1024), blk, 0, stream>>>((const float4*)parts, (float4*)d_out);
}

// Round 18
// 327.773 us; speedup vs baseline: 1.0984x; 1.0984x over previous
//
#include <hip/hip_runtime.h>
#include <math.h>

// ---------------------------------------------------------------------------
// b=1, S=1024, H=16, D=64, HID=1024. All f32; pos int32; out f32.
// Passing R10-R16 semantics (absmax ~7e-3). This round: REVERT round-17's
// BK=32 qkv (measured +24us: A-staging ac=(tid&3)*8 put all 4 tid&3 groups
// on bank 0 mod 32 -> 4-way write conflict, 786K->3.9M; 51KB LDS cut
// occupancy 24->17.5%). Back to the round-12/16 proven-best config
// (333.2/336.0us across two runs):
//  - qkv_s48 split-K kc=384 panels, BK=16, 4+4@+64 conflict-free (89us)
//  - combine_rope fused fold+rotate (bit-identical, kills a 16MB pass)
//  - score 64x64 round-0 structure (K=64 too short for 64x128)
//  - select_agg6 strided wave-per-row (ballot rank/compaction)
//  - GIN: gemm64<1> silu + gemm64<2> residual (2.0 B/FMA)
//  - out: gemm64<0> split-K=2 + combine_out
// ---------------------------------------------------------------------------
#define NEGF  -1e30f
#define TAU   1e-6f

static __device__ __forceinline__ int imin(int a, int b) { return a < b ? a : b; }

static __device__ __forceinline__ void fma44(float A[4][4], const float4 xa, const float4 yb) {
  A[0][0] += xa.x * yb.x; A[0][1] += xa.x * yb.y; A[0][2] += xa.x * yb.z; A[0][3] += xa.x * yb.w;
  A[1][0] += xa.y * yb.x; A[1][1] += xa.y * yb.y; A[1][2] += xa.y * yb.z; A[1][3] += xa.y * yb.w;
  A[2][0] += xa.z * yb.x; A[2][1] += xa.z * yb.y; A[2][2] += xa.z * yb.z; A[2][3] += xa.z * yb.w;
  A[3][0] += xa.w * yb.x; A[3][1] += xa.w * yb.y; A[3][2] += xa.w * yb.z; A[3][3] += xa.w * yb.w;
}

static __device__ __forceinline__ void fold44(float T[4][4], float A[4][4]) {
#pragma unroll
  for (int e = 0; e < 4; ++e)
#pragma unroll
    for (int f = 0; f < 4; ++f) { T[e][f] = __fadd_rn(T[e][f], A[e][f]); A[e][f] = 0.0f; }
}

// ---------------------------------------------------------------------------
// f32 GEMM, 64x64 tile, 256 threads, 4x4/thread, BK=16, sequential FMA over k.
// MODE 0: plain f32; 1: silu; 2: +eps*R residual. Batched via blockIdx.z.
// ---------------------------------------------------------------------------
template <int MODE>
__global__ __launch_bounds__(256) void gemm64(
    const float* __restrict__ A, const float* __restrict__ B, float* __restrict__ C,
    const float* __restrict__ R, const float* __restrict__ eps_p,
    int M, int N, int K, int lda, int ldb, int ldc,
    long sA, long sB, long sC)
{
  const int z = blockIdx.z;
  A += (long)z * sA;
  B += (long)z * sB;
  float* Cf = C + (long)z * sC;
  const float* Rz = (MODE == 2) ? (R + (long)z * sC) : nullptr;

  const int bm = blockIdx.x * 64;
  const int bn = blockIdx.y * 64;
  const int tid = threadIdx.x;
  const int r0 = (tid >> 4) * 4;
  const int c0 = (tid & 15) * 4;

  __shared__ float As[16][68];
  __shared__ float Bs[16][64];

  float acc[4][4] = {};

  const int ar = tid >> 2;
  const int ac = (tid & 3) * 4;
  const int br = tid >> 4;
  const int bc = (tid & 15) * 4;

  for (int kt = 0; kt < K; kt += 16) {
    float4 av = *(const float4*)(A + (long)(bm + ar) * lda + kt + ac);
    float4 bv = *(const float4*)(B + (long)(kt + br) * ldb + bn + bc);
    As[ac + 0][ar] = av.x;
    As[ac + 1][ar] = av.y;
    As[ac + 2][ar] = av.z;
    As[ac + 3][ar] = av.w;
    *(float4*)&Bs[br][bc] = bv;
    __syncthreads();
#pragma unroll
    for (int kk = 0; kk < 16; ++kk) {
      const float4 xa = *(const float4*)&As[kk][r0];
      const float4 yb = *(const float4*)&Bs[kk][c0];
      fma44(acc, xa, yb);
    }
    __syncthreads();
  }

  const float ev = (MODE == 2) ? eps_p[0] : 0.0f;
#pragma unroll
  for (int e = 0; e < 4; ++e)
#pragma unroll
    for (int f = 0; f < 4; ++f) {
      const int r = bm + r0 + e;
      const int c = bn + c0 + f;
      float x = acc[e][f];
      if (MODE == 1) x = x / (1.0f + expf(-x));
      if (MODE == 2) x += ev * Rz[(long)r * ldc + c];
      Cf[(long)r * ldc + c] = x;
    }
}

// ---------------------------------------------------------------------------
// Split-K QKV, 64x128 tile, 4x8 fragments (4+4 cols split at +64 — bank
// conflict-free), BK=16 double-buffered. Grid (16,8,9): z -> (mat, panel).
// ---------------------------------------------------------------------------
__global__ __launch_bounds__(256) void gemm_qkv_s48(
    const float* __restrict__ A,
    const float* __restrict__ Wq, const float* __restrict__ Wk, const float* __restrict__ Wv,
    float* __restrict__ part)
{
  const int z = blockIdx.z;
  const int mat = z % 3;
  const int panel = z / 3;
  const float* B = (mat == 0) ? Wq : (mat == 1) ? Wk : Wv;
  float* P = part + ((long)(mat * 3 + panel) << 20);

  const int k0 = panel * 384;
  const int k1 = (panel == 2) ? 1024 : (k0 + 384);

  const int bm = blockIdx.x * 64;
  const int bn = blockIdx.y * 128;
  const int tid = threadIdx.x;
  const int r0 = (tid >> 4) * 4;    // 4 rows
  const int c0 = (tid & 15) * 4;    // cols c0 and c0+64

  __shared__ float As[2][16][68];
  __shared__ float Bs[2][16][132];

  float aL[4][4] = {}, aR[4][4] = {};

  const int ar = tid >> 2;          // 0..63 A row
  const int ac = (tid & 3) * 4;     // 0,4,8,12 A k-chunk
  const int br = tid >> 4;          // 0..15 B k-row
  const int bc = (tid & 15) * 4;    // B cols bc and bc+64

  {
    float4 av = *(const float4*)(A + (long)(bm + ar) * 1024 + k0 + ac);
    float4 b0 = *(const float4*)(B + (long)(k0 + br) * 1024 + bn + bc);
    float4 b1 = *(const float4*)(B + (long)(k0 + br) * 1024 + bn + bc + 64);
    As[0][ac + 0][ar] = av.x; As[0][ac + 1][ar] = av.y;
    As[0][ac + 2][ar] = av.z; As[0][ac + 3][ar] = av.w;
    *(float4*)&Bs[0][br][bc] = b0;
    *(float4*)&Bs[0][br][bc + 64] = b1;
  }
  __syncthreads();

  int cur = 0;
  for (int kt = k0; kt < k1; kt += 16) {
    const bool more = (kt + 16 < k1);
    float4 avn, b0n, b1n;
    if (more) {
      avn = *(const float4*)(A + (long)(bm + ar) * 1024 + kt + 16 + ac);
      b0n = *(const float4*)(B + (long)(kt + 16 + br) * 1024 + bn + bc);
      b1n = *(const float4*)(B + (long)(kt + 16 + br) * 1024 + bn + bc + 64);
    }
#pragma unroll
    for (int kk = 0; kk < 16; ++kk) {
      const float4 xa = *(const float4*)&As[cur][kk][r0];
      const float4 y0 = *(const float4*)&Bs[cur][kk][c0];
      const float4 y1 = *(const float4*)&Bs[cur][kk][64 + c0];
      fma44(aL, xa, y0);
      fma44(aR, xa, y1);
    }
    if (more) {
      const int nxt = cur ^ 1;
      As[nxt][ac + 0][ar] = avn.x; As[nxt][ac + 1][ar] = avn.y;
      As[nxt][ac + 2][ar] = avn.z; As[nxt][ac + 3][ar] = avn.w;
      *(float4*)&Bs[nxt][br][bc] = b0n;
      *(float4*)&Bs[nxt][br][bc + 64] = b1n;
      __syncthreads();
      cur = nxt;
    }
  }

#pragma unroll
  for (int e = 0; e < 4; ++e) {
    float* prow = P + (long)(bm + r0 + e) * 1024 + bn;
#pragma unroll
    for (int f = 0; f < 4; ++f) {
      prow[c0 + f]      = aL[e][f];
      prow[64 + c0 + f] = aR[e][f];
    }
  }
}

// ---------------------------------------------------------------------------
// Fused panel-combine + RoPE. Bit-identical to combine_qkv -> rope_apply.
// ---------------------------------------------------------------------------
__global__ __launch_bounds__(256) void combine_rope(
    const float4* __restrict__ part, const float2* __restrict__ tab,
    float4* __restrict__ q, float4* __restrict__ k, float4* __restrict__ v)
{
  const int g = blockIdx.x * 256 + threadIdx.x;
  if (g < 262144) {
    const int buf = g >> 17;            // 0=q, 1=k
    const int rem = g & 131071;
    const int s   = rem >> 7;
    const int hx  = (rem >> 3) & 15;
    const int t4  = rem & 7;
    const int w   = s * 256 + hx * 16 + t4;   // float4 idx of lo (d in [0,32))
    const long b  = (long)(buf * 3) << 18;

    const float4 a0 = part[b + w];
    const float4 a1 = part[b + (1L << 18) + w];
    const float4 a2 = part[b + (2L << 18) + w];
    const float4 c0 = part[b + w + 8];
    const float4 c1 = part[b + (1L << 18) + w + 8];
    const float4 c2 = part[b + (2L << 18) + w + 8];

    float lo[4], hi[4];
    lo[0] = __fadd_rn(__fadd_rn(a0.x, a1.x), a2.x);
    lo[1] = __fadd_rn(__fadd_rn(a0.y, a1.y), a2.y);
    lo[2] = __fadd_rn(__fadd_rn(a0.z, a1.z), a2.z);
    lo[3] = __fadd_rn(__fadd_rn(a0.w, a1.w), a2.w);
    hi[0] = __fadd_rn(__fadd_rn(c0.x, c1.x), c2.x);
    hi[1] = __fadd_rn(__fadd_rn(c0.y, c1.y), c2.y);
    hi[2] = __fadd_rn(__fadd_rn(c0.z, c1.z), c2.z);
    hi[3] = __fadd_rn(__fadd_rn(c0.w, c1.w), c2.w);

    float ol[4], oh[4];
#pragma unroll
    for (int c = 0; c < 4; ++c) {
      const int t = t4 * 4 + c;
      const float2 cs = tab[s * 32 + t];
      const float x1 = lo[c];
      const float x2 = hi[c];
      ol[c] = __fadd_rn(__fmul_rn(x1, cs.x), __fmul_rn(-x2, cs.y));
      oh[c] = __fadd_rn(__fmul_rn(x2, cs.x), __fmul_rn(x1, cs.y));
    }
    float4* dst = buf ? k : q;
    dst[w]     = make_float4(ol[0], ol[1], ol[2], ol[3]);
    dst[w + 8] = make_float4(oh[0], oh[1], oh[2], oh[3]);
  } else {
    const int w = g - 262144;           // 0..262143
    const long b = (long)6 << 18;
    const float4 s0 = part[b + w];
    const float4 s1 = part[b + (1L << 18) + w];
    const float4 s2 = part[b + (2L << 18) + w];
    float4 r;
    r.x = __fadd_rn(__fadd_rn(s0.x, s1.x), s2.x);
    r.y = __fadd_rn(__fadd_rn(s0.y, s1.y), s2.y);
    r.z = __fadd_rn(__fadd_rn(s0.z, s1.z), s2.z);
    r.w = __fadd_rn(__fadd_rn(s0.w, s1.w), s2.w);
    v[w] = r;
  }
}

// ---------------------------------------------------------------------------
// gemm_out split-K combine: dst = fl(p0 + p1), 1M floats as float4.
// ---------------------------------------------------------------------------
__global__ __launch_bounds__(256) void combine_out(
    const float4* __restrict__ p, float4* __restrict__ dst)
{
  const int idx = blockIdx.x * 256 + threadIdx.x;   // 0..262143
  const float4 a = p[idx];
  const float4 b = p[idx + (1 << 18)];
  float4 r;
  r.x = __fadd_rn(a.x, b.x);
  r.y = __fadd_rn(a.y, b.y);
  r.z = __fadd_rn(a.z, b.z);
  r.w = __fadd_rn(a.w, b.w);
  dst[idx] = r;
}

// ---------------------------------------------------------------------------
// Fallback fused QKV (round-0 proven). Used when workspace < 64MB.
// ---------------------------------------------------------------------------
__global__ __launch_bounds__(256) void gemm_qkv64(
    const float* __restrict__ A,
    const float* __restrict__ Wq, const float* __restrict__ Wk, const float* __restrict__ Wv,
    float* __restrict__ qo, float* __restrict__ ko, float* __restrict__ vo)
{
  const int z = blockIdx.z;
  const float* B = (z == 0) ? Wq : (z == 1) ? Wk : Wv;
  float* C = (z == 0) ? qo : (z == 1) ? ko : vo;

  const int bm = blockIdx.x * 64;
  const int bn = blockIdx.y * 64;
  const int tid = threadIdx.x;
  const int r0 = (tid >> 4) * 4;
  const int c0 = (tid & 15) * 4;

  __shared__ float As[2][32][68];
  __shared__ float Bs[2][32][64];

  float acc[4][4] = {};
  float tot[4][4] = {};

  const int ar = tid >> 2;
  const int ac = (tid & 3) * 8;
  const int br = tid >> 3;
  const int bc = (tid & 7) * 8;

  {
    float4 a0 = *(const float4*)(A + (long)(bm + ar) * 1024 + ac);
    float4 a1 = *(const float4*)(A + (long)(bm + ar) * 1024 + ac + 4);
    float4 b0 = *(const float4*)(B + (long)br * 1024 + bn + bc);
    float4 b1 = *(const float4*)(B + (long)br * 1024 + bn + bc + 4);
    As[0][ac + 0][ar] = a0.x; As[0][ac + 1][ar] = a0.y;
    As[0][ac + 2][ar] = a0.z; As[0][ac + 3][ar] = a0.w;
    As[0][ac + 4][ar] = a1.x; As[0][ac + 5][ar] = a1.y;
    As[0][ac + 6][ar] = a1.z; As[0][ac + 7][ar] = a1.w;
    *(float4*)&Bs[0][br][bc] = b0;
    *(float4*)&Bs[0][br][bc + 4] = b1;
  }
  __syncthreads();

  int cur = 0;
  for (int kt = 0; kt < 1024; kt += 32) {
    const bool more = (kt + 32 < 1024);
    float4 a0n, a1n, b0n, b1n;
    if (more) {
      a0n = *(const float4*)(A + (long)(bm + ar) * 1024 + kt + 32 + ac);
      a1n = *(const float4*)(A + (long)(bm + ar) * 1024 + kt + 32 + ac + 4);
      b0n = *(const float4*)(B + (long)(kt + 32 + br) * 1024 + bn + bc);
      b1n = *(const float4*)(B + (long)(kt + 32 + br) * 1024 + bn + bc + 4);
    }
    if (kt == 384 || kt == 768) {
      fold44(tot, acc);
    }
#pragma unroll
    for (int kk = 0; kk < 32; ++kk) {
      const float4 xa = *(const float4*)&As[cur][kk][r0];
      const float4 yb = *(const float4*)&Bs[cur][kk][c0];
      fma44(acc, xa, yb);
    }
    if (more) {
      const int nxt = cur ^ 1;
      As[nxt][ac + 0][ar] = a0n.x; As[nxt][ac + 1][ar] = a0n.y;
      As[nxt][ac + 2][ar] = a0n.z; As[nxt][ac + 3][ar] = a0n.w;
      As[nxt][ac + 4][ar] = a1n.x; As[nxt][ac + 5][ar] = a1n.y;
      As[nxt][ac + 6][ar] = a1n.z; As[nxt][ac + 7][ar] = a1n.w;
      *(float4*)&Bs[nxt][br][bc] = b0n;
      *(float4*)&Bs[nxt][br][bc + 4] = b1n;
      __syncthreads();
      cur = nxt;
    }
  }

#pragma unroll
  for (int e = 0; e < 4; ++e)
#pragma unroll
    for (int f = 0; f < 4; ++f)
      C[(long)(bm + r0 + e) * 1024 + bn + c0 + f] = __fadd_rn(tot[e][f], acc[e][f]);
}

// ---------------------------------------------------------------------------
// RoPE cos/sin table: bit-identical double-path math.
// ---------------------------------------------------------------------------
__global__ __launch_bounds__(256) void rope_table(
    const int* __restrict__ pos_ids, float2* __restrict__ tab)
{
  const int g = blockIdx.x * 256 + threadIdx.x;   // 0..32767
  const int t = g & 31;
  const int s = g >> 5;

  const float e = (float)(2 * t) / 64.0f;
  const float p32 = (float)pow(10000.0, (double)e);
  const float inv = __fdiv_rn(1.0f, p32);
  const float posf = (float)pos_ids[s];
  const float ang = __fmul_rn(posf, inv);
  tab[g] = make_float2((float)cos((double)ang), (float)sin((double)ang));
}

// ---------------------------------------------------------------------------
// RoPE apply (memory-only). Fallback path only.
// ---------------------------------------------------------------------------
__global__ __launch_bounds__(256) void rope_apply(float* __restrict__ q,
                                                  float* __restrict__ kb,
                                                  const float2* __restrict__ tab)
{
  const int g = blockIdx.x * blockDim.x + threadIdx.x;
  const int t = g & 31;
  const int h = (g >> 5) & 15;
  const int s = (g >> 9) & 1023;
  const int buf = g >> 19;
  float* p = buf ? kb : q;

  const float2 cs = tab[s * 32 + t];
  const float c  = cs.x;
  const float sn = cs.y;

  const int base = s * 1024 + h * 64;
  const float x1 = p[base + t];
  const float x2 = p[base + t + 32];
  p[base + t]      = __fadd_rn(__fmul_rn(x1, c), __fmul_rn(-x2, sn));
  p[base + t + 32] = __fadd_rn(__fmul_rn(x2, c), __fmul_rn(x1, sn));
}

// ---------------------------------------------------------------------------
// Score GEMM (round-0 proven), causal lower-triangle 64x64 tiles (136/head).
// ---------------------------------------------------------------------------
__global__ __launch_bounds__(256) void gemm_score(
    const float* __restrict__ q, const float* __restrict__ kb,
    float* __restrict__ S, int headBase)
{
  const int x = blockIdx.x;
  int bmT = 0;
  while ((bmT + 1) * (bmT + 2) / 2 <= x) ++bmT;
  const int bnT = x - bmT * (bmT + 1) / 2;

  const int hl = blockIdx.y;
  const int off = (headBase + hl) * 64;
  const int bm = bmT * 64;
  const int bn = bnT * 64;
  const int tid = threadIdx.x;
  const int r0 = (tid >> 4) * 4;
  const int c0 = (tid & 15) * 4;

  __shared__ float As[16][68];
  __shared__ float Bs[16][68];

  float acc[4][4] = {};

  const int ar = tid >> 2;
  const int ac = (tid & 3) * 4;

  for (int kt = 0; kt < 64; kt += 16) {
    float4 av = *(const float4*)(q  + (long)(bm + ar) * 1024 + off + kt + ac);
    float4 bv = *(const float4*)(kb + (long)(bn + ar) * 1024 + off + kt + ac);
    As[ac + 0][ar] = av.x; As[ac + 1][ar] = av.y;
    As[ac + 2][ar] = av.z; As[ac + 3][ar] = av.w;
    Bs[ac + 0][ar] = bv.x; Bs[ac + 1][ar] = bv.y;
    Bs[ac + 2][ar] = bv.z; Bs[ac + 3][ar] = bv.w;
    __syncthreads();
#pragma unroll
    for (int kk = 0; kk < 16; ++kk) {
      const float4 xa = *(const float4*)&As[kk][r0];
      const float4 yb = *(const float4*)&Bs[kk][c0];
      fma44(acc, xa, yb);
    }
    __syncthreads();
  }

#pragma unroll
  for (int e = 0; e < 4; ++e)
#pragma unroll
    for (int f = 0; f < 4; ++f)
      S[((long)hl * 1024 + bm + r0 + e) * 1024 + bn + c0 + f] = acc[e][f] * 0.125f;
}

// ---------------------------------------------------------------------------
// Selection + aggregation, WAVE-PER-ROW, STRIDED layout (agg6, round-12).
// ---------------------------------------------------------------------------
#define UFV(m) ((raw[m] >= 0.2f) ? __float_as_uint(raw[m]) : 0u)

__global__ __launch_bounds__(256) void select_agg6(
    const float* __restrict__ S, const float* __restrict__ v,
    float* __restrict__ comb, int headBase)
{
  const int tid = threadIdx.x;
  const int lane = tid & 63;
  const int wid = tid >> 6;
  const int i = blockIdx.x * 4 + wid;     // row 0..1023
  const int hl = blockIdx.y;
  const int h = headBase + hl;

  __shared__ int histS[4][256];
  __shared__ unsigned listS[4][128];
  int* hist = histS[wid];
  unsigned* list = listS[wid];

  const int nlayer = (i + 63) >> 6;       // wave-uniform layer count
  const unsigned long long ltm = (1ull << lane) - 1ull;

  // ---- load row: layer m, j = 64m + lane (coalesced 256B/layer) ----
  const float* row = S + ((long)hl * 1024 + i) * 1024;
  float raw[16];
#pragma unroll
  for (int m = 0; m < 16; ++m) raw[m] = 0.0f;
#pragma unroll
  for (int m = 0; m < 16; ++m) {
    if (m < nlayer) {
      const int j = m * 64 + lane;
      if (j < i) raw[m] = row[j];
    }
  }

  const int kk = (i > 0) ? (i + 9) / 10 : 0;
  unsigned V = 0u;
  int need_eq = 0;
  unsigned fmask = 0u;

  if (kk > 0) {
    // ---- pass-0 packed counts over the only possible top bytes ----
    int c3E = 0, c3F = 0, cHI = 0;
    bool anyBig = false;
#pragma unroll
    for (int m = 0; m < 16; ++m) {
      if (m < nlayer) {
        const unsigned u = UFV(m);
        if (u != 0u) {
          const unsigned tb = u >> 24;
          if (tb == 0x3Eu) ++c3E;
          else if (tb == 0x3Fu) ++c3F;
          else { ++cHI; if (tb > 0x40u) anyBig = true; }
        }
      }
    }
    const bool fastOK = (__ballot(anyBig) == 0ull);
    unsigned pk = (unsigned)c3E | ((unsigned)c3F << 10) | ((unsigned)cHI << 20);
#pragma unroll
    for (int off = 1; off < 64; off <<= 1)
      pk += (unsigned)__shfl_xor((int)pk, off, 64);
    const int t3E = (int)(pk & 1023u);
    const int t3F = (int)((pk >> 10) & 1023u);
    const int tHI = (int)((pk >> 20) & 1023u);
    const int totNZ = t3E + t3F + tHI;

    unsigned prefix = 0;
    int rk = kk;
    bool done = false;
    for (int pass = 0; pass < 4 && !done; ++pass) {
      const int shift = 24 - 8 * pass;
      if (pass == 0 && fastOK) {
        if (totNZ < rk) {
          V = 0u; need_eq = rk - totNZ; done = true;
        } else {
          int selBin, scnt;
          if (tHI >= rk)            { selBin = 0x40; scnt = tHI; }
          else if (tHI + t3F >= rk) { selBin = 0x3F; scnt = t3F; rk -= tHI; }
          else                      { selBin = 0x3E; scnt = t3E; rk -= tHI + t3F; }
          prefix = (unsigned)selBin;
          if (rk == scnt) {
            unsigned vm = 0xFFFFFFFFu;
#pragma unroll
            for (int m = 0; m < 16; ++m) {
              if (m < nlayer) {
                const unsigned u = UFV(m);
                if (u != 0u && (u >> shift) == prefix && u < vm) vm = u;
              }
            }
#pragma unroll
            for (int off = 1; off < 64; off <<= 1) {
              const unsigned o = (unsigned)__shfl_xor((int)vm, off, 64);
              if (o < vm) vm = o;
            }
            V = vm; need_eq = 0x3FFFFFFF; done = true;
          }
        }
        continue;
      }
      // ---- generic pass (atomic hist; pass 0 only via fallback) ----
      *(int4*)&hist[lane * 4] = make_int4(0, 0, 0, 0);
      asm volatile("s_waitcnt lgkmcnt(0)" ::: "memory");
      __builtin_amdgcn_sched_barrier(0);
#pragma unroll
      for (int m = 0; m < 16; ++m) {
        if (m < nlayer) {
          const unsigned u = UFV(m);
          if (u != 0u && (pass == 0 || (u >> (shift + 8)) == prefix))
            atomicAdd(&hist[(u >> shift) & 0xFF], 1);
        }
      }
      asm volatile("s_waitcnt lgkmcnt(0)" ::: "memory");
      __builtin_amdgcn_sched_barrier(0);
      const int4 hv = *(const int4*)&hist[lane * 4];
      const int s = hv.x + hv.y + hv.z + hv.w;
      int suf = s;
#pragma unroll
      for (int off = 1; off < 64; off <<= 1) {
        const int o = __shfl_down(suf, off, 64);
        if (lane + off < 64) suf += o;
      }
      const int tot = __shfl(suf, 0, 64);
      if (pass == 0 && tot < rk) {
        V = 0u; need_eq = rk - tot; done = true;
      } else {
        const int above = suf - s;
        const int sfx3 = above + hv.w;
        const int sfx2 = sfx3 + hv.z;
        const int sfx1 = sfx2 + hv.y;
        const int sfx0 = suf;
        int mbin = -1, mh = 0, msfx = 0;
        if (!(pass == 0 && lane == 0) && sfx0 >= rk && sfx0 - hv.x < rk) { mbin = lane * 4 + 0; mh = hv.x; msfx = sfx0; }
        if (sfx1 >= rk && sfx1 - hv.y < rk) { mbin = lane * 4 + 1; mh = hv.y; msfx = sfx1; }
        if (sfx2 >= rk && sfx2 - hv.z < rk) { mbin = lane * 4 + 2; mh = hv.z; msfx = sfx2; }
        if (sfx3 >= rk && sfx3 - hv.w < rk) { mbin = lane * 4 + 3; mh = hv.w; msfx = sfx3; }
        const unsigned long long bal = __ballot(mbin >= 0);
        const int src = (int)__ffsll((unsigned long long)bal) - 1;
        const int selBin = __shfl(mbin, src, 64) & 0xFF;
        const int scnt = __shfl(mh, src, 64);
        const int ssfx = __shfl(msfx, src, 64);
        prefix = (prefix << 8) | (unsigned)selBin;
        rk = rk - (ssfx - scnt);
        if (rk == scnt) {
          unsigned vm = 0xFFFFFFFFu;
#pragma unroll
          for (int m = 0; m < 16; ++m) {
            if (m < nlayer) {
              const unsigned u = UFV(m);
              if (u != 0u && (u >> shift) == prefix && u < vm) vm = u;
            }
          }
#pragma unroll
          for (int off = 1; off < 64; off <<= 1) {
            const unsigned o = (unsigned)__shfl_xor((int)vm, off, 64);
            if (o < vm) vm = o;
          }
          V = vm; need_eq = 0x3FFFFFFF; done = true;
        }
      }
    }
    if (!done) { V = prefix; need_eq = rk; }

    // ---- f0 flags + stable tie-break via per-layer ballots (j order) ----
    int prefEq = 0;
#pragma unroll
    for (int m = 0; m < 16; ++m) {
      if (m < nlayer) {
        const int j = m * 64 + lane;
        const bool validm = (j < i);
        const unsigned u = UFV(m);
        const bool eq = validm && (u == V);
        const unsigned long long bal = __ballot(eq);
        if (validm) {
          if (u > V) fmask |= (1u << m);
          else if (eq) {
            const int excl = prefEq + __popcll(bal & ltm);
            if (excl < need_eq) fmask |= (1u << m);
          }
        }
        prefEq += (int)__popcll(bal);
      }
    }
  }

  // ---- ambiguity hypothesis (all wave-level reduces; uniform result) ----
  int hypOut = -1, hypIn = -1;
  if (kk > 0 && kk < i) {
    unsigned wmax = 0u;
    int mIn = -1;
    unsigned long long tbIn = ~0ull, tbOut = ~0ull;
#pragma unroll
    for (int m = 0; m < 16; ++m) {
      if (m < nlayer) {
        const int j = m * 64 + lane;
        if (j < i) {
          const unsigned u = UFV(m);
          if ((fmask >> m) & 1u) {
            if (u == V && j > mIn) mIn = j;
            const float fv = __uint_as_float(u);
            const float dd = fv - 0.2f;
            if (fv >= 0.2f && dd < TAU) {
              const unsigned long long p = (((unsigned long long)__float_as_uint(dd)) << 32) | (unsigned)j;
              if (p < tbIn) tbIn = p;
            }
          } else {
            if (u > wmax) wmax = u;
            if (raw[m] < 0.2f) {
              const float dd = 0.2f - raw[m];
              if (dd < TAU) {
                const unsigned long long p = (((unsigned long long)__float_as_uint(dd)) << 32) | (unsigned)j;
                if (p < tbOut) tbOut = p;
              }
            }
          }
        }
      }
    }
#pragma unroll
    for (int off = 1; off < 64; off <<= 1) {
      const unsigned ow = (unsigned)__shfl_xor((int)wmax, off, 64);
      if (ow > wmax) wmax = ow;
      const int om = __shfl_xor(mIn, off, 64);
      if (om > mIn) mIn = om;
      const unsigned long long oi = __shfl_xor(tbIn, off, 64);
      if (oi < tbIn) tbIn = oi;
      const unsigned long long oo = __shfl_xor(tbOut, off, 64);
      if (oo < tbOut) tbOut = oo;
    }
    int outMin = 0x7FFFFFFF;
#pragma unroll
    for (int m = 0; m < 16; ++m) {
      if (m < nlayer) {
        const int j = m * 64 + lane;
        if (j < i && !((fmask >> m) & 1u) && UFV(m) == wmax) {
          if (j < outMin) outMin = j;
        }
      }
    }
#pragma unroll
    for (int off = 1; off < 64; off <<= 1) {
      const int o = __shfl_xor(outMin, off, 64);
      if (o < outMin) outMin = o;
    }
    float bestD = TAU;
    int oI = -1, nI = -1;
    if (outMin != 0x7FFFFFFF && mIn >= 0) {
      const float Vf = __uint_as_float(V);
      const float Wf = __uint_as_float(wmax);
      if (!(wmax == V && V == 0u)) {
        const float gapA = Vf - Wf;
        if (gapA < bestD) { bestD = gapA; oI = mIn; nI = outMin; }
      }
      if (tbIn != ~0ull) {
        const float d = __uint_as_float((unsigned)(tbIn >> 32));
        const int jj = (int)(tbIn & 0xFFFFFFFFu);
        const bool noop = (wmax == 0u && jj < outMin);
        if (!noop && d < bestD) { bestD = d; oI = jj; nI = outMin; }
      }
      if (tbOut != ~0ull && Vf <= 0.2f) {
        const float d = __uint_as_float((unsigned)(tbOut >> 32));
        const int jj = (int)(tbOut & 0xFFFFFFFFu);
        if (d < bestD) { bestD = d; oI = mIn; nI = jj; }
      }
    }
    hypOut = oI; hypIn = nI;
  }

  // ---- compaction (j-ascending) via per-layer ballots ----
  const bool amb = (hypOut >= 0);
  int base = 0;
#pragma unroll
  for (int m = 0; m < 16; ++m) {
    if (m < nlayer) {
      const int j = m * 64 + lane;
      const bool validm = (j < i);
      const unsigned f0b = (fmask >> m) & 1u;
      int s1 = (int)f0b;
      if (amb) { if (j == hypOut) s1 = 0; if (j == hypIn) s1 = 1; }
      const bool sel = validm && ((f0b | (unsigned)s1) != 0u);
      const unsigned long long bal = __ballot(sel);
      if (sel) {
        const int pos = base + (int)__popcll(bal & ltm);
        list[pos] = (unsigned)j | (f0b << 10) | ((unsigned)s1 << 11);
      }
      base += (int)__popcll(bal);
    }
  }
  const int L = base;   // wave-uniform
  asm volatile("s_waitcnt lgkmcnt(0)" ::: "memory");
  __builtin_amdgcn_sched_barrier(0);

  const float denom = (float)(kk > 0 ? kk : 1);
  const float* vcol = v + h * 64 + lane;
  float* crow = comb + ((long)(h * 1024 + i)) * 256;

  if (!amb) {
    float sum0 = 0, sq0 = 0, mx0 = NEGF;
    for (int e2 = 0; e2 < L; e2 += 4) {
      const uint4 en4 = *(const uint4*)&list[e2];
      float v0 = 0, v1 = 0, v2 = 0, v3 = 0;
      const bool b0 = (e2 + 0 < L), b1 = (e2 + 1 < L), b2 = (e2 + 2 < L), b3 = (e2 + 3 < L);
      if (b0) v0 = vcol[(long)(en4.x & 1023) * 1024];
      if (b1) v1 = vcol[(long)(en4.y & 1023) * 1024];
      if (b2) v2 = vcol[(long)(en4.z & 1023) * 1024];
      if (b3) v3 = vcol[(long)(en4.w & 1023) * 1024];
      if (b0) { sum0 += v0; sq0 += v0 * v0; mx0 = fmaxf(mx0, v0); }
      if (b1) { sum0 += v1; sq0 += v1 * v1; mx0 = fmaxf(mx0, v1); }
      if (b2) { sum0 += v2; sq0 += v2 * v2; mx0 = fmaxf(mx0, v2); }
      if (b3) { sum0 += v3; sq0 += v3 * v3; mx0 = fmaxf(mx0, v3); }
    }
    const float mean0 = sum0 / denom;
    const float var0 = fmaxf(sq0 / denom - mean0 * mean0, 0.0f);
    const float mx0o = (kk > 0) ? mx0 : 0.0f;
    crow[lane]       = sum0;
    crow[64 + lane]  = mean0;
    crow[128 + lane] = mx0o;
    crow[192 + lane] = var0;
  } else {
    float sum0 = 0, sq0 = 0, mx0 = NEGF, sum1 = 0, sq1 = 0, mx1 = NEGF;
    for (int e2 = 0; e2 < L; e2 += 4) {
      const uint4 en4 = *(const uint4*)&list[e2];
      const unsigned w0 = (e2 + 0 < L) ? en4.x : 0u;
      const unsigned w1 = (e2 + 1 < L) ? en4.y : 0u;
      const unsigned w2 = (e2 + 2 < L) ? en4.z : 0u;
      const unsigned w3 = (e2 + 3 < L) ? en4.w : 0u;
      float v0 = 0, v1 = 0, v2 = 0, v3 = 0;
      if (w0) v0 = vcol[(long)(w0 & 1023) * 1024];
      if (w1) v1 = vcol[(long)(w1 & 1023) * 1024];
      if (w2) v2 = vcol[(long)(w2 & 1023) * 1024];
      if (w3) v3 = vcol[(long)(w3 & 1023) * 1024];
      if (w0 & (1u << 10)) { sum0 += v0; sq0 += v0 * v0; mx0 = fmaxf(mx0, v0); }
      if (w0 & (1u << 11)) { sum1 += v0; sq1 += v0 * v0; mx1 = fmaxf(mx1, v0); }
      if (w1 & (1u << 10)) { sum0 += v1; sq0 += v1 * v1; mx0 = fmaxf(mx0, v1); }
      if (w1 & (1u << 11)) { sum1 += v1; sq1 += v1 * v1; mx1 = fmaxf(mx1, v1); }
      if (w2 & (1u << 10)) { sum0 += v2; sq0 += v2 * v2; mx0 = fmaxf(mx0, v2); }
      if (w2 & (1u << 11)) { sum1 += v2; sq1 += v2 * v2; mx1 = fmaxf(mx1, v2); }
      if (w3 & (1u << 10)) { sum0 += v3; sq0 += v3 * v3; mx0 = fmaxf(mx0, v3); }
      if (w3 & (1u << 11)) { sum1 += v3; sq1 += v3 * v3; mx1 = fmaxf(mx1, v3); }
    }
    const float mean0 = sum0 / denom, mean1 = sum1 / denom;
    const float var0 = fmaxf(sq0 / denom - mean0 * mean0, 0.0f);
    const float var1 = fmaxf(sq1 / denom - mean1 * mean1, 0.0f);
    const float mx0o = (kk > 0) ? mx0 : 0.0f;
    const float mx1o = (kk > 0) ? mx1 : 0.0f;
    crow[lane]       = 0.5f * (sum0 + sum1);
    crow[64 + lane]  = 0.5f * (mean0 + mean1);
    crow[128 + lane] = 0.5f * (mx0o + mx1o);
    crow[192 + lane] = 0.5f * (var0 + var1);
  }
}

// ---------------------------------------------------------------------------
// Launch
// ---------------------------------------------------------------------------
extern "C" void kernel_launch(void* const* d_in, const int* in_sizes, int n_in,
                              void* d_out, int out_size, void* d_ws, size_t ws_size,
                              hipStream_t stream)
{
  const float* hidden = (const float*)d_in[0];
  const float* Wq = (const float*)d_in[1];
  const float* Wk = (const float*)d_in[2];
  const float* Wv = (const float*)d_in[3];
  const float* Wo = (const float*)d_in[4];
  const float* W1 = (const float*)d_in[5];
  const float* W2 = (const float*)d_in[6];
  const float* eps = (const float*)d_in[7];
  const int* pos = (const int*)d_in[8];

  const size_t MB = 1024UL * 1024UL;
  int G = 4;
  if (ws_size >= 28 * MB + 64 * MB) G = 16;
  else if (ws_size >= 28 * MB + 32 * MB) G = 8;

  float* q      = (float*)d_ws;
  float* kbuf   = q + (1 << 20);
  float* v      = kbuf + (1 << 20);
  float* comb   = v + (1 << 20);
  float* scores = comb + (1 << 22);
  float* h1     = scores;               // overlay (scores dead after select)
  float* ho     = scores + (1 << 21);
  // Overlays on comb (16MB):
  //  - rope table (256KB): used before select writes comb.
  //  - gemm_out partials (8MB): used after gemm64<1> consumed comb.
  float2* tab   = (float2*)comb;
  float* parts  = comb;

  const dim3 blk(256);

  rope_table<<<128, blk, 0, stream>>>(pos, tab);

  if (ws_size >= 64 * MB) {
    // split-K over kc=384 panels; partials (36MB) overlay scores region;
    // fused combine+rope writes rotated q/k and plain v.
    float* part = scores;
    gemm_qkv_s48<<<dim3(16, 8, 9), blk, 0, stream>>>(hidden, Wq, Wk, Wv, part);
    combine_rope<<<2048, blk, 0, stream>>>((const float4*)part, tab,
                                           (float4*)q, (float4*)kbuf, (float4*)v);
  } else {
    gemm_qkv64<<<dim3(16, 16, 3), blk, 0, stream>>>(hidden, Wq, Wk, Wv, q, kbuf, v);
    rope_apply<<<4096, blk, 0, stream>>>(q, kbuf, tab);
  }

  for (int g = 0; g < 16; g += G) {
    gemm_score<<<dim3(136, G), blk, 0, stream>>>(q, kbuf, scores, g);
    select_agg6<<<dim3(256, G), blk, 0, stream>>>(scores, v, comb, g);
  }

  gemm64<1><<<dim3(16, 2, 16), blk, 0, stream>>>(comb, W1, h1, nullptr, nullptr,
      1024, 128, 256, 256, 128, 128, (long)1024 * 256, (long)256 * 128, (long)1024 * 128);

  gemm64<2><<<dim3(16, 1, 16), blk, 0, stream>>>(h1, W2, ho, v, eps,
      1024, 64, 128, 128, 64, 1024, (long)1024 * 128, (long)128 * 64, 64);

  // Output projection: 64x64 tile, split-K=2 (z picks k-half), then combine.
  gemm64<0><<<dim3(16, 16, 2), blk, 0, stream>>>(ho, Wo, parts, nullptr, nullptr,
      1024, 1024, 512, 1024, 1024, 1024, 512, (long)512 * 1024, (long)1 << 20);
  combine_out<<<dim3(1024), blk, 0, stream>>>((const float4*)parts, (float4*)d_out);
}